// Round 1
// 79.276 us; speedup vs baseline: 1.0557x; 1.0557x over previous
//
#include <hip/hip_runtime.h>

typedef float v2f __attribute__((ext_vector_type(2)));

constexpr int H = 512, W = 512;   // fixed by the problem (4,3,512,512)
constexpr int K = 5, PADR = 2;

__device__ __forceinline__ float rfl(float v) {
    union { float f; int i; } u; u.f = v;
    u.i = __builtin_amdgcn_readfirstlane(u.i);
    return u.f;
}

// map squared spatial distance {0,1,2,4,5,8} -> compact index 0..5
constexpr int idx6(int d2) {
    return d2 == 0 ? 0 : d2 == 1 ? 1 : d2 == 2 ? 2 : d2 == 4 ? 3 : d2 == 5 ? 4 : 5;
}

// 8 pixels/thread along W. Row-streaming: process window rows in order
// {2,0,1,3,4} (center first), so only ONE 12-wide row (~16 VGPR) is live at a
// time instead of the whole 5x12 window (60 VGPR). Halo handled with 4 aligned
// float4 loads + cndmask selects (no scalar gathers). Spatial kernel collapsed
// to its 6 distinct Gaussian values, held uniform via readfirstlane.
__global__ __launch_bounds__(256) void bilateral_kernel(
    const float* __restrict__ x,
    const float* __restrict__ sk,
    const float* __restrict__ sigma_color,
    float* __restrict__ out)
{
    int t = threadIdx.x;

    // 6 distinct spatial weights by symmetry: d2 = {0,1,2,4,5,8} at flat
    // positions {12, 7, 6, 2, 1, 0}. log2 once, broadcast to SGPRs.
    float lw[6];
    lw[0] = rfl(__builtin_amdgcn_logf(sk[12]));
    lw[1] = rfl(__builtin_amdgcn_logf(sk[7]));
    lw[2] = rfl(__builtin_amdgcn_logf(sk[6]));
    lw[3] = rfl(__builtin_amdgcn_logf(sk[2]));
    lw[4] = rfl(__builtin_amdgcn_logf(sk[1]));
    lw[5] = rfl(__builtin_amdgcn_logf(sk[0]));

    float s = sigma_color[0];                          // wave-uniform
    float c2 = -1.4426950408889634f / (2.0f * s * s);  // -log2(e)/(2s^2)
    v2f c2v = { c2, c2 };

    int gid = blockIdx.x * 256 + t;
    int p0 = gid << 3;                 // first of 8 pixels (grid exactly covers)
    int w0 = p0 & (W - 1);             // multiple of 8 -> float4 aligned
    int row = p0 >> 9;
    int h = row & (H - 1);
    int plane = row >> 9;
    const float* xp = x + (size_t)plane * (H * W);

    bool lane0 = (w0 == 0);            // left image edge (lane 0 of each wave)
    bool laneN = (w0 == W - 8);        // right image edge (lane 63)
    int wL = lane0 ? 0        : (w0 - 4);   // aligned left halo vec4
    int wR = laneN ? (w0 + 4) : (w0 + 8);   // aligned right halo vec4

    v2f cc[4], ws[4], acc[4];
#pragma unroll
    for (int q = 0; q < 4; ++q) { ws[q] = (v2f){0.f, 0.f}; acc[q] = (v2f){0.f, 0.f}; }

    constexpr int order[K] = {2, 0, 1, 3, 4};   // center row first -> cc ready
#pragma unroll
    for (int oi = 0; oi < K; ++oi) {
        const int i = order[oi];
        // reflected row offset (np 'reflect': -1 -> 1, H -> H-2)
        int hv = h + i - PADR;
        hv = (hv < 0) ? -hv : hv;
        hv = (hv >= H) ? (2 * H - 2 - hv) : hv;
        const float* rp = xp + (hv << 9);

        float4 a  = *(const float4*)(rp + wL);
        float4 m0 = *(const float4*)(rp + w0);
        float4 m1 = *(const float4*)(rp + w0 + 4);
        float4 b  = *(const float4*)(rp + wR);

        float win[12];
        // left halo: interior = prev chunk's tail; edge reflect -2->2, -1->1
        win[0]  = lane0 ? m0.z : a.z;
        win[1]  = lane0 ? m0.y : a.w;
        win[2]  = m0.x; win[3] = m0.y; win[4] = m0.z; win[5] = m0.w;
        win[6]  = m1.x; win[7] = m1.y; win[8] = m1.z; win[9] = m1.w;
        // right halo: interior = next chunk's head; edge reflect 512->510, 513->509
        win[10] = laneN ? m1.z : b.x;
        win[11] = laneN ? m1.y : b.y;

        if (oi == 0) {                 // i==2: capture center pixel values
#pragma unroll
            for (int q = 0; q < 4; ++q) {
                cc[q][0] = win[2 * q + 2];
                cc[q][1] = win[2 * q + 3];
            }
        }

#pragma unroll
        for (int j = 0; j < K; ++j) {
            const float lwv = lw[idx6((i - 2) * (i - 2) + (j - 2) * (j - 2))];
            v2f lsp = { lwv, lwv };
#pragma unroll
            for (int q = 0; q < 4; ++q) {
                v2f v = { win[2 * q + j], win[2 * q + j + 1] };
                v2f d = v - cc[q];
                v2f arg = __builtin_elementwise_fma(d * c2v, d, lsp);
                v2f wq;
                wq[0] = __builtin_amdgcn_exp2f(arg[0]);
                wq[1] = __builtin_amdgcn_exp2f(arg[1]);
                ws[q] += wq;
                acc[q] = __builtin_elementwise_fma(wq, v, acc[q]);
            }
        }
    }

    float4 o0, o1;
    o0.x = acc[0][0] * __builtin_amdgcn_rcpf(ws[0][0] + 1e-8f);
    o0.y = acc[0][1] * __builtin_amdgcn_rcpf(ws[0][1] + 1e-8f);
    o0.z = acc[1][0] * __builtin_amdgcn_rcpf(ws[1][0] + 1e-8f);
    o0.w = acc[1][1] * __builtin_amdgcn_rcpf(ws[1][1] + 1e-8f);
    o1.x = acc[2][0] * __builtin_amdgcn_rcpf(ws[2][0] + 1e-8f);
    o1.y = acc[2][1] * __builtin_amdgcn_rcpf(ws[2][1] + 1e-8f);
    o1.z = acc[3][0] * __builtin_amdgcn_rcpf(ws[3][0] + 1e-8f);
    o1.w = acc[3][1] * __builtin_amdgcn_rcpf(ws[3][1] + 1e-8f);
    *(float4*)(out + p0)     = o0;
    *(float4*)(out + p0 + 4) = o1;
}

extern "C" void kernel_launch(void* const* d_in, const int* in_sizes, int n_in,
                              void* d_out, int out_size, void* d_ws, size_t ws_size,
                              hipStream_t stream) {
    const float* x  = (const float*)d_in[0];
    const float* sk = (const float*)d_in[1];
    const float* sc = (const float*)d_in[2];
    float* out = (float*)d_out;

    const int total = in_sizes[0];             // 3,145,728 elements
    const int blocks = total / (256 * 8);      // 1536, exact cover
    bilateral_kernel<<<blocks, 256, 0, stream>>>(x, sk, sc, out);
}

// Round 2
// 78.476 us; speedup vs baseline: 1.0665x; 1.0102x over previous
//
#include <hip/hip_runtime.h>

typedef float v2f __attribute__((ext_vector_type(2)));

constexpr int H = 512, W = 512;   // fixed by the problem (4,3,512,512)
constexpr int K = 5, PADR = 2;
constexpr int ROWS = 4;           // output rows per block
constexpr int SROWS = ROWS + 4;   // staged input rows (r0-2 .. r0+5)

__device__ __forceinline__ float rfl(float v) {
    union { float f; int i; } u; u.f = v;
    u.i = __builtin_amdgcn_readfirstlane(u.i);
    return u.f;
}

// map squared spatial distance {0,1,2,4,5,8} -> compact index 0..5
constexpr int idx6(int d2) {
    return d2 == 0 ? 0 : d2 == 1 ? 1 : d2 == 2 ? 2 : d2 == 4 ? 3 : d2 == 5 ? 4 : 5;
}

// Tile kernel: block = 4 output rows x 512 cols (8 px/thread, wave = one row).
// The 8 input rows the tile needs are staged to LDS with 4 coalesced
// global_load_dwordx4 per thread (was 20 per thread reading globally) ->
// VMEM latency paid once behind one barrier; window reads are ds_read_b128.
// launch_bounds(256,4) pins VGPR<=128 so occupancy can't fall off the cliff.
__global__ __launch_bounds__(256, 4) void bilateral_kernel(
    const float* __restrict__ x,
    const float* __restrict__ sk,
    const float* __restrict__ sigma_color,
    float* __restrict__ out)
{
    __shared__ float lds[SROWS][W];   // 16 KB

    int t = threadIdx.x;
    int wave = t >> 6;
    int l = t & 63;

    // 6 distinct spatial weights by symmetry: d2 = {0,1,2,4,5,8} at flat
    // positions {12, 7, 6, 2, 1, 0}. log2 once, broadcast to SGPRs.
    float lw[6];
    lw[0] = rfl(__builtin_amdgcn_logf(sk[12]));
    lw[1] = rfl(__builtin_amdgcn_logf(sk[7]));
    lw[2] = rfl(__builtin_amdgcn_logf(sk[6]));
    lw[3] = rfl(__builtin_amdgcn_logf(sk[2]));
    lw[4] = rfl(__builtin_amdgcn_logf(sk[1]));
    lw[5] = rfl(__builtin_amdgcn_logf(sk[0]));

    float s = sigma_color[0];                          // wave-uniform
    float c2 = -1.4426950408889634f / (2.0f * s * s);  // -log2(e)/(2s^2)
    v2f c2v = { c2, c2 };

    int plane = blockIdx.x >> 7;          // 12 planes (B*C)
    int r0 = (blockIdx.x & 127) * ROWS;   // first output row of tile
    const float* xp = x + (size_t)plane * (H * W);

    // ---- stage 8 rows: wave w loads rows {w, w+4}, lane l -> cols 8l..8l+7
#pragma unroll
    for (int kk = 0; kk < 2; ++kk) {
        int k = wave + 4 * kk;
        int gr = r0 - 2 + k;              // np 'reflect': -1 -> 1, H -> H-2
        gr = (gr < 0) ? -gr : gr;
        gr = (gr >= H) ? (2 * H - 2 - gr) : gr;
        const float* src = xp + (gr << 9) + (l << 3);
        float4 v0 = *(const float4*)(src);
        float4 v1 = *(const float4*)(src + 4);
        *(float4*)(&lds[k][l << 3])     = v0;
        *(float4*)(&lds[k][(l << 3) + 4]) = v1;
    }
    __syncthreads();

    // ---- compute: wave rr handles output row r0+rr, lane l -> cols 8l..8l+7
    int rr = wave;
    int w0 = l << 3;

    bool lane0 = (l == 0);            // left image edge
    bool laneN = (l == 63);           // right image edge
    int wL = lane0 ? 0       : (w0 - 4);   // aligned left halo vec4
    int wR = laneN ? (w0 + 4) : (w0 + 8);  // aligned right halo vec4

    v2f cc[4], ws[4], acc[4];
#pragma unroll
    for (int q = 0; q < 4; ++q) { ws[q] = (v2f){0.f, 0.f}; acc[q] = (v2f){0.f, 0.f}; }

    constexpr int order[K] = {2, 0, 1, 3, 4};   // center row first -> cc ready
#pragma unroll
    for (int oi = 0; oi < K; ++oi) {
        const int i = order[oi];
        const float* rp = &lds[rr + i][0];

        float4 a  = *(const float4*)(rp + wL);
        float4 m0 = *(const float4*)(rp + w0);
        float4 m1 = *(const float4*)(rp + w0 + 4);
        float4 b  = *(const float4*)(rp + wR);

        float win[12];
        // left halo: interior = prev chunk's tail; edge reflect -2->2, -1->1
        win[0]  = lane0 ? m0.z : a.z;
        win[1]  = lane0 ? m0.y : a.w;
        win[2]  = m0.x; win[3] = m0.y; win[4] = m0.z; win[5] = m0.w;
        win[6]  = m1.x; win[7] = m1.y; win[8] = m1.z; win[9] = m1.w;
        // right halo: interior = next chunk's head; edge reflect 512->510, 513->509
        win[10] = laneN ? m1.z : b.x;
        win[11] = laneN ? m1.y : b.y;

        if (oi == 0) {                 // i==2: capture center pixel values
#pragma unroll
            for (int q = 0; q < 4; ++q) {
                cc[q][0] = win[2 * q + 2];
                cc[q][1] = win[2 * q + 3];
            }
        }

#pragma unroll
        for (int j = 0; j < K; ++j) {
            const float lwv = lw[idx6((i - 2) * (i - 2) + (j - 2) * (j - 2))];
            v2f lsp = { lwv, lwv };
#pragma unroll
            for (int q = 0; q < 4; ++q) {
                v2f v = { win[2 * q + j], win[2 * q + j + 1] };
                v2f d = v - cc[q];
                v2f arg = __builtin_elementwise_fma(d * c2v, d, lsp);
                v2f wq;
                wq[0] = __builtin_amdgcn_exp2f(arg[0]);
                wq[1] = __builtin_amdgcn_exp2f(arg[1]);
                ws[q] += wq;
                acc[q] = __builtin_elementwise_fma(wq, v, acc[q]);
            }
        }
    }

    float* op = out + (size_t)plane * (H * W) + ((r0 + rr) << 9) + w0;
    float4 o0, o1;
    o0.x = acc[0][0] * __builtin_amdgcn_rcpf(ws[0][0] + 1e-8f);
    o0.y = acc[0][1] * __builtin_amdgcn_rcpf(ws[0][1] + 1e-8f);
    o0.z = acc[1][0] * __builtin_amdgcn_rcpf(ws[1][0] + 1e-8f);
    o0.w = acc[1][1] * __builtin_amdgcn_rcpf(ws[1][1] + 1e-8f);
    o1.x = acc[2][0] * __builtin_amdgcn_rcpf(ws[2][0] + 1e-8f);
    o1.y = acc[2][1] * __builtin_amdgcn_rcpf(ws[2][1] + 1e-8f);
    o1.z = acc[3][0] * __builtin_amdgcn_rcpf(ws[3][0] + 1e-8f);
    o1.w = acc[3][1] * __builtin_amdgcn_rcpf(ws[3][1] + 1e-8f);
    *(float4*)(op)     = o0;
    *(float4*)(op + 4) = o1;
}

extern "C" void kernel_launch(void* const* d_in, const int* in_sizes, int n_in,
                              void* d_out, int out_size, void* d_ws, size_t ws_size,
                              hipStream_t stream) {
    const float* x  = (const float*)d_in[0];
    const float* sk = (const float*)d_in[1];
    const float* sc = (const float*)d_in[2];
    float* out = (float*)d_out;

    const int total = in_sizes[0];              // 3,145,728 elements
    const int blocks = total / (256 * 8);       // 1536 = 12 planes * 128 tiles
    bilateral_kernel<<<blocks, 256, 0, stream>>>(x, sk, sc, out);
}